// Round 9
// baseline (58.985 us; speedup 1.0000x reference)
//
#include <hip/hip_runtime.h>

// Problem constants (fixed by setup_inputs)
#define NB 16          // graphs
#define NN 256         // nodes per graph
#define ND 64          // emb dim
#define EPG 4096       // edges per graph
#define NE (NB*EPG)    // 65536 edges
#define MAXE_ROW 256   // max possible edges per row (distinct dst, no self-loop)

typedef float f4 __attribute__((ext_vector_type(4)));
typedef int   i4 __attribute__((ext_vector_type(4)));

// One block per output row. Self-contained: scan graph's src list -> LDS edge
// list + LDS bitmask; masked contiguous row fill; copy own edges. No global
// scratch, no memset, no inter-block ordering. Single dispatch.
__global__ __launch_bounds__(256) void row_kernel(const float* __restrict__ edge_attr,
                                                  const int* __restrict__ edge_index,
                                                  const float* __restrict__ emb,
                                                  f4* __restrict__ out) {
    __shared__ unsigned lmask[8];      // 256-bit column mask for this row
    __shared__ int      lcnt;
    __shared__ int      llist[MAXE_ROW];  // (e << 8) | ld
    const int row = blockIdx.x;        // global row 0..4095
    const int g   = row >> 8;          // graph
    const int tid = threadIdx.x;

    if (tid < 8) lmask[tid] = 0u;
    if (tid == 0) lcnt = 0;
    __syncthreads();

    // ---- scan this graph's src array (4096 ints = 1024 int4; L1/L2-resident)
    const i4* __restrict__ srcv = (const i4*)(edge_index + g * EPG);
    #pragma unroll
    for (int k = 0; k < 4; ++k) {
        const int vi = tid + k * 256;              // int4 index 0..1023
        const i4 s = srcv[vi];
        #pragma unroll
        for (int j = 0; j < 4; ++j) {
            if (s[j] == row) {                     // this edge starts at our row
                const int e  = g * EPG + vi * 4 + j;
                const int ld = edge_index[NE + e] & (NN - 1);
                atomicOr(&lmask[ld >> 5], 1u << (ld & 31));
                const int p = atomicAdd(&lcnt, 1);
                llist[p] = (e << 8) | ld;
            }
        }
    }
    __syncthreads();

    // ---- masked fill of non-edge cells (64 KB contiguous row)
    const int ci = tid >> 4;                       // cell within pass
    const int dq = tid & 15;                       // f4 slot within cell
    const f4 v1 = ((const f4*)(emb + 1 * ND))[dq]; // diagonal
    const f4 v2 = ((const f4*)(emb + 2 * ND))[dq]; // disconnected
    const int diag = row & (NN - 1);
    f4* __restrict__ rowout = out + (long)row * NN * (ND / 4);
    unsigned w[8];
    #pragma unroll
    for (int k = 0; k < 8; ++k) w[k] = lmask[k];   // LDS broadcast reads
    #pragma unroll
    for (int pass = 0; pass < 16; ++pass) {        // 4 KB contiguous per pass
        const int col = pass * 16 + ci;
        const unsigned bits = w[pass >> 1] >> ((pass & 1) * 16);
        if (!((bits >> ci) & 1u))
            rowout[col * (ND / 4) + dq] = (col == diag) ? v1 : v2;
    }

    // ---- copy this row's edges (mean 16 per row; 16 lanes per edge)
    const int cnt = lcnt;
    for (int k = tid >> 4; k < cnt; k += 16) {
        const int pk = llist[k];
        const int e  = pk >> 8;
        const int ld = pk & 255;
        rowout[ld * (ND / 4) + dq] = ((const f4*)edge_attr)[(long)e * (ND / 4) + dq];
    }
}

extern "C" void kernel_launch(void* const* d_in, const int* in_sizes, int n_in,
                              void* d_out, int out_size, void* d_ws, size_t ws_size,
                              hipStream_t stream) {
    const float* edge_attr  = (const float*)d_in[0];
    const float* emb_table  = (const float*)d_in[1];
    const int*   edge_index = (const int*)d_in[2];
    // d_in[3] = batch_vec — unused (indices derivable from src/dst bit math)
    f4* out = (f4*)d_out;

    row_kernel<<<NB * NN, 256, 0, stream>>>(edge_attr, edge_index, emb_table, out);
}